// Round 13
// baseline (329.068 us; speedup 1.0000x reference)
//
#include <hip/hip_runtime.h>
#include <hip/hip_bf16.h>
#include <stdint.h>

typedef short bf16x8 __attribute__((ext_vector_type(8)));
typedef float f32x4  __attribute__((ext_vector_type(4)));
typedef unsigned short u16x4 __attribute__((ext_vector_type(4)));
typedef unsigned int   u32x2 __attribute__((ext_vector_type(2)));

#define DEV __device__ __forceinline__

DEV ushort f2bf(float f){
  unsigned u = __float_as_uint(f);
  u += 0x7FFFu + ((u >> 16) & 1u);      // RNE
  return (ushort)(u >> 16);
}

DEV unsigned pack_bf16x2(float lo, float hi){
  __hip_bfloat162 r = __float22bfloat162_rn(float2{lo, hi});   // v_cvt_pk_bf16_f32
  return *(unsigned*)&r;
}

DEV void async16(const void* g, void* l){
  __builtin_amdgcn_global_load_lds((const __attribute__((address_space(1))) void*)g,
                                   (__attribute__((address_space(3))) void*)l, 16, 0, 0);
}

// ---------------------------------------------- fused preprocessing
// blocks [0,16384): LayerNorm row      -> xn (bf16)
// blocks [16384,17152): Wqkv^T tile    -> Wqt (bf16, 3072x1024)
// blocks [17152,17408): Wout^T tile    -> Wot (bf16, 1024x1024)
// blocks [17408,17472): rope cos/sin   -> cst (float2, 1024x16)
__global__ __launch_bounds__(256) void preproc_kernel(
    const float* __restrict__ x, const float* __restrict__ gamma,
    const float* __restrict__ beta, ushort* __restrict__ xn,
    const float* __restrict__ Wqkv, ushort* __restrict__ Wqt,
    const float* __restrict__ Wout, ushort* __restrict__ Wot,
    const float* __restrict__ rope, float2* __restrict__ cst)
{
  __shared__ __align__(16) ushort tile[64][65];
  __shared__ float red[8];
  const int b = blockIdx.x, t = threadIdx.x;
  if (b < 16384) {                     // ---- LayerNorm
    const float4* xr = (const float4*)(x + (size_t)b * 1024);
    float4 v = xr[t];
    float s  = v.x + v.y + v.z + v.w;
    float s2 = v.x*v.x + v.y*v.y + v.z*v.z + v.w*v.w;
    #pragma unroll
    for (int o = 1; o < 64; o <<= 1) { s += __shfl_xor(s, o); s2 += __shfl_xor(s2, o); }
    int lane = t & 63, wv = t >> 6;
    if (lane == 0) { red[wv] = s; red[4 + wv] = s2; }
    __syncthreads();
    s  = red[0] + red[1] + red[2] + red[3];
    s2 = red[4] + red[5] + red[6] + red[7];
    float mean = s * (1.0f / 1024.0f);
    float var  = s2 * (1.0f / 1024.0f) - mean * mean;
    float rs = rsqrtf(var + 1e-5f);
    float4 g = ((const float4*)gamma)[t], bb = ((const float4*)beta)[t];
    u16x4 o4;
    o4[0] = f2bf((v.x - mean) * rs * g.x + bb.x);
    o4[1] = f2bf((v.y - mean) * rs * g.y + bb.y);
    o4[2] = f2bf((v.z - mean) * rs * g.z + bb.z);
    o4[3] = f2bf((v.w - mean) * rs * g.w + bb.w);
    ((u16x4*)(xn + (size_t)b * 1024))[t] = o4;
  } else if (b < 17408) {              // ---- W transposes (fp32 -> bf16)
    const float* A; ushort* At; int R, C, c0, r0;
    if (b < 17152) { int bb2 = b - 16384; A = Wqkv; At = Wqt; R = 1024; C = 3072;
                     c0 = (bb2 % 48) * 64; r0 = (bb2 / 48) * 64; }
    else           { int bb2 = b - 17152; A = Wout; At = Wot; R = 1024; C = 1024;
                     c0 = (bb2 % 16) * 64; r0 = (bb2 / 16) * 64; }
    int tx = t & 63, ty = t >> 6;
    #pragma unroll
    for (int i = 0; i < 64; i += 4)
      tile[ty + i][tx] = f2bf(A[(size_t)(r0 + ty + i) * C + c0 + tx]);
    __syncthreads();
    #pragma unroll
    for (int i = 0; i < 64; i += 4)
      At[(size_t)(c0 + ty + i) * R + r0 + tx] = tile[tx][ty + i];
  } else {                             // ---- rope tables
    int i = (b - 17408) * 256 + t;     // 16384 = 1024 l * 16 d
    int l = i >> 4, d = i & 15;
    float p = rope[l * 32 + d];
    float s, c;
    sincosf(p, &s, &c);
    cst[i] = float2{c, s};
  }
}

// ------------------------------------------------- bf16 GEMM (R5-proven loop)
// 256x256 tile, BK=64, 8 waves (2Mx4N), K-plane LDS [buf][kc][256][64B],
// counted vmcnt(4) pipeline. ROUND-MAJOR mapping (1 block/CU => each round's
// 2MB B-stripe is L2-resident). ROPE epilogue: rotate cols<2048, pre-scale q
// (cols<1024) by 0.125*log2(e); V columns (>=2048) are written DIRECTLY into
// the transposed vT[bh][d][l] layout (eliminates the vtrans kernel).
template<bool OUT_BF16, bool HAS_BIAS, bool ROPE>
__global__ __launch_bounds__(512, 2) void gemm256_kernel(
    const ushort* __restrict__ A, const ushort* __restrict__ Bt,
    const float* __restrict__ bias, void* __restrict__ Cout,
    const float2* __restrict__ cst, ushort* __restrict__ vTo,
    int M, int Nrow, int K)
{
  __shared__ __align__(16) ushort As[2][2][256][32];   // 64 KiB
  __shared__ __align__(16) ushort Bs[2][2][256][32];   // 64 KiB
  const int tid = threadIdx.x, lane = tid & 63, w = tid >> 6;
  const int fr = lane & 15, fg = lane >> 4;
  const int wr = w >> 2, wc = w & 3;

  // round-major + XCD-contiguous within round
  int i  = blockIdx.x & 255;
  int r  = blockIdx.x >> 8;
  int il = (i & 7) * 32 + (i >> 3);
  int bx = r * 4 + (il & 3);
  int by = il >> 2;
  const int aRow0 = by * 256, bCol0 = bx * 256;
  const size_t ldb = (size_t)K * 2;   // row bytes

  // ---- staging constants (2 load-groups per wave, 16 rows x 64B each)
  const int lrow = lane >> 2, lch = lane & 3;
  const int g0 = w * 2, g1 = w * 2 + 1;
  const int r0 = g0 * 16 + lrow, r1 = g1 * 16 + lrow;
  const int sc0 = ((lch ^ ((r0 & 3) ^ ((r0 >> 2) & 3))) << 4);
  const int sc1 = ((lch ^ ((r1 & 3) ^ ((r1 >> 2) & 3))) << 4);
  const char* Ab = (const char*)A + (size_t)aRow0 * ldb;
  const char* Bb = (const char*)Bt + (size_t)bCol0 * ldb;
  const size_t ga0 = (size_t)r0 * ldb, ga1 = (size_t)r1 * ldb;
  char* ldsA = (char*)&As[0][0][0][0];
  char* ldsB = (char*)&Bs[0][0][0][0];
  const int ld0 = g0 * 1024, ld1 = g1 * 1024;

  // ---- fragment read byte-offsets (within a plane)
  int rbA[8], rbB[4];
  #pragma unroll
  for (int mf = 0; mf < 8; ++mf) {
    int rr = wr * 128 + mf * 16 + fr;
    rbA[mf] = rr * 64 + ((fg ^ ((rr & 3) ^ ((rr >> 2) & 3))) << 4);
  }
  #pragma unroll
  for (int nf = 0; nf < 4; ++nf) {
    int rr = wc * 64 + nf * 16 + fr;
    rbB[nf] = rr * 64 + ((fg ^ ((rr & 3) ^ ((rr >> 2) & 3))) << 4);
  }

  f32x4 acc[8][4];
  f32x4 z = {0.f, 0.f, 0.f, 0.f};
  #pragma unroll
  for (int mf = 0; mf < 8; ++mf)
    #pragma unroll
    for (int nf = 0; nf < 4; ++nf) acc[mf][nf] = z;

  auto stage = [&](int buf, int kt, int kc) {
    const char* ak = Ab + (size_t)kt * 128 + kc * 64;
    const char* bk = Bb + (size_t)kt * 128 + kc * 64;
    int lo = buf * 32768 + kc * 16384;
    async16(ak + ga0 + sc0, ldsA + lo + ld0);
    async16(ak + ga1 + sc1, ldsA + lo + ld1);
    async16(bk + ga0 + sc0, ldsB + lo + ld0);
    async16(bk + ga1 + sc1, ldsB + lo + ld1);
  };

  // prologue: stage tile 0 (both planes), wait first plane, enter loop
  stage(0, 0, 0);
  stage(0, 0, 1);
  asm volatile("s_waitcnt vmcnt(4)" ::: "memory");
  __builtin_amdgcn_s_barrier();

  const int nk = K >> 6;
  for (int kt = 0; kt < nk; ++kt) {
    int buf = kt & 1;
    bool pre = (kt + 1 < nk);
    #pragma unroll
    for (int kc = 0; kc < 2; ++kc) {
      const char* ab = ldsA + buf * 32768 + kc * 16384;
      const char* bb = ldsB + buf * 32768 + kc * 16384;
      bf16x8 a[8], b[4];
      #pragma unroll
      for (int mf = 0; mf < 8; ++mf) a[mf] = *(const bf16x8*)(ab + rbA[mf]);
      #pragma unroll
      for (int nf = 0; nf < 4; ++nf) b[nf] = *(const bf16x8*)(bb + rbB[nf]);
      if (pre) stage(buf ^ 1, kt + 1, kc);
      __builtin_amdgcn_s_setprio(1);
      #pragma unroll
      for (int mf = 0; mf < 8; ++mf)
        #pragma unroll
        for (int nf = 0; nf < 4; ++nf)
          acc[mf][nf] = __builtin_amdgcn_mfma_f32_16x16x32_bf16(a[mf], b[nf], acc[mf][nf], 0, 0, 0);
      __builtin_amdgcn_s_setprio(0);
      if (pre) { asm volatile("s_waitcnt vmcnt(4)" ::: "memory"); }
      else     { asm volatile("s_waitcnt vmcnt(0)" ::: "memory"); }
      __builtin_amdgcn_s_barrier();
    }
  }

  // ---- epilogue
  #pragma unroll
  for (int pr = 0; pr < 2; ++pr) {
    int nf0 = pr * 2, nf1 = nf0 + 1;
    int gc0 = bCol0 + wc * 64 + nf0 * 16 + fr;
    int gc1 = gc0 + 16;
    float bv0 = HAS_BIAS ? bias[gc0] : 0.0f;
    float bv1 = HAS_BIAS ? bias[gc1] : 0.0f;
    bool rot = ROPE && (pr == 0) && (gc0 < 2048);
    bool isv = ROPE && (gc0 >= 2048);
    float qs = (ROPE && gc0 < 1024) ? 0.18033688f : 1.0f;   // 0.125*log2(e)
    #pragma unroll
    for (int mf = 0; mf < 8; ++mf) {
      int gr0 = aRow0 + wr * 128 + mf * 16 + fg * 4;
      #pragma unroll
      for (int rr2 = 0; rr2 < 4; ++rr2) {
        int gr = gr0 + rr2;
        float a = acc[mf][nf0][rr2] + bv0;
        float b = acc[mf][nf1][rr2] + bv1;
        if (rot) {
          int l = gr & 1023;
          float2 cp = cst[l * 16 + fr];
          float an = fmaf(a, cp.x, -b * cp.y);
          b = fmaf(b, cp.x, a * cp.y);
          a = an;
        }
        a *= qs; b *= qs;
        if (isv) {
          // direct transposed store into vT[bh][d][l]
          int d0 = gc0 - 2048;
          int bhv = ((gr >> 10) << 4) + (d0 >> 6);
          size_t vb = (size_t)bhv * 65536 + (size_t)(d0 & 63) * 1024 + (gr & 1023);
          vTo[vb]             = f2bf(a);
          vTo[vb + 16 * 1024] = f2bf(b);
        } else if (OUT_BF16) {
          ((ushort*)Cout)[(size_t)gr * Nrow + gc0] = f2bf(a);
          ((ushort*)Cout)[(size_t)gr * Nrow + gc1] = f2bf(b);
        } else {
          ((float*)Cout)[(size_t)gr * Nrow + gc0] = a;
          ((float*)Cout)[(size_t)gr * Nrow + gc1] = b;
        }
      }
    }
  }
}

// ---------------------------------------------------------------- Flash attention v7 (R11-proven, 132us)
// 256 thr / 4 waves, QBLK=128; defer-max, exp2-domain, cvt_pk P-pack,
// ones-MFMA l on the matrix pipe; 3 blocks/CU.
__global__ __launch_bounds__(256, 3) void attn_kernel(
    const ushort* __restrict__ qkv, const ushort* __restrict__ vT,
    ushort* __restrict__ aout)
{
  __shared__ __align__(16) ushort Ks[2][64 * 64];
  __shared__ __align__(16) ushort Vs[2][64 * 64];   // Vs[d][kv]
  __shared__ __align__(16) ushort Ps[4][32 * 64];   // per-wave P
  const int tid = threadIdx.x, lane = tid & 63, w = tid >> 6;
  const int fr = lane & 15, fg = lane >> 4;
  const int bh = blockIdx.x & 255, qt = blockIdx.x >> 8;  // same-bh -> same XCD
  const int bt = bh >> 4, h = bh & 15;
  const size_t ld = 3072;
  const ushort* qbase = qkv + (size_t)bt * 1024 * ld + h * 64;
  const ushort* kbase = qbase + 1024;
  const ushort* vtb = vT + (size_t)bh * 64 * 1024;
  const int srow = lane >> 3;
  const int scol = (((lane & 7) ^ srow) << 4);
  const int swz = (fr & 7) << 4;

  bf16x8 ones;
  #pragma unroll
  for (int j = 0; j < 8; ++j) ones[j] = (short)0x3F80;   // 1.0 bf16

  // Q fragments straight from global (one-time; reused 16 tiles)
  bf16x8 qfr[2][2];
  #pragma unroll
  for (int qf = 0; qf < 2; ++qf)
    #pragma unroll
    for (int kc = 0; kc < 2; ++kc) {
      int qrow = qt * 128 + w * 32 + qf * 16 + fr;
      qfr[qf][kc] = *(const bf16x8*)((const char*)(qbase + (size_t)qrow * ld) + kc * 64 + fg * 16);
    }

  f32x4 o[2][4], ls[2];
  f32x4 z = {0.f, 0.f, 0.f, 0.f};
  #pragma unroll
  for (int a = 0; a < 2; ++a) {
    ls[a] = z;
    #pragma unroll
    for (int b = 0; b < 4; ++b) o[a][b] = z;
  }
  float m_[2] = {-1e30f, -1e30f};

  auto stage = [&](int buf, int t) {
    #pragma unroll
    for (int i = 0; i < 2; ++i) {
      int ch = w * 2 + i;                 // 8 chunks of 1KB each for K and V
      async16((const char*)(kbase + (size_t)(t * 64 + ch * 8 + srow) * ld) + scol,
              (char*)Ks[buf] + ch * 1024);
      async16((const char*)(vtb + (size_t)(ch * 8 + srow) * 1024) + t * 128 + scol,
              (char*)Vs[buf] + ch * 1024);
    }
  };

  stage(0, 0);
  __syncthreads();
  for (int t = 0; t < 16; ++t) {
    int cur = t & 1;
    if (t + 1 < 16) stage(cur ^ 1, t + 1);   // overlaps compute below

    bf16x8 kf[4][2];
    #pragma unroll
    for (int kvf = 0; kvf < 4; ++kvf)
      #pragma unroll
      for (int kc = 0; kc < 2; ++kc)
        kf[kvf][kc] = *(const bf16x8*)((const char*)Ks[cur] + (kvf * 16 + fr) * 128 +
                                       ((kc * 64 + fg * 16) ^ swz));
    float alpha[2] = {1.0f, 1.0f};
    int   need[2];
    #pragma unroll
    for (int qf = 0; qf < 2; ++qf) {
      f32x4 st[4];
      #pragma unroll
      for (int kvf = 0; kvf < 4; ++kvf) st[kvf] = z;
      __builtin_amdgcn_s_setprio(1);
      #pragma unroll
      for (int kc = 0; kc < 2; ++kc)
        #pragma unroll
        for (int kvf = 0; kvf < 4; ++kvf)
          st[kvf] = __builtin_amdgcn_mfma_f32_16x16x32_bf16(kf[kvf][kc], qfr[qf][kc], st[kvf], 0, 0, 0);
      __builtin_amdgcn_s_setprio(0);
      float mx = -1e30f;
      #pragma unroll
      for (int kvf = 0; kvf < 4; ++kvf)
        #pragma unroll
        for (int r = 0; r < 4; ++r) mx = fmaxf(mx, st[kvf][r]);
      mx = fmaxf(mx, __shfl_xor(mx, 16));
      mx = fmaxf(mx, __shfl_xor(mx, 32));
      // defer-max: only advance running max when tile max exceeds it by >11.53
      // (log2-domain; P then bounded by 2^11.53 ~= e^8 -- bf16-safe)
      need[qf] = __any(mx > m_[qf] + 11.53f);
      if (need[qf]) {
        float mn = fmaxf(m_[qf], mx);
        alpha[qf] = __builtin_amdgcn_exp2f(m_[qf] - mn);
        m_[qf] = mn;
      }
      float mb = m_[qf];
      int qrow = qf * 16 + fr;
      #pragma unroll
      for (int kvf = 0; kvf < 4; ++kvf) {
        float p0 = __builtin_amdgcn_exp2f(st[kvf][0] - mb);
        float p1 = __builtin_amdgcn_exp2f(st[kvf][1] - mb);
        float p2 = __builtin_amdgcn_exp2f(st[kvf][2] - mb);
        float p3 = __builtin_amdgcn_exp2f(st[kvf][3] - mb);
        u32x2 u;
        u[0] = pack_bf16x2(p0, p1);
        u[1] = pack_bf16x2(p2, p3);
        *(u32x2*)((char*)Ps[w] + qrow * 128 + ((kvf * 32 + fg * 8) ^ swz)) = u;
      }
    }
    #pragma unroll
    for (int of = 0; of < 2; ++of) {
      if (need[of]) {                          // wave-uniform branch
        float ar[4];
        #pragma unroll
        for (int r = 0; r < 4; ++r) ar[r] = __shfl(alpha[of], fg * 4 + r);
        #pragma unroll
        for (int cf = 0; cf < 4; ++cf)
          #pragma unroll
          for (int r = 0; r < 4; ++r) o[of][cf][r] *= ar[r];
        #pragma unroll
        for (int r = 0; r < 4; ++r) ls[of][r] *= ar[r];
      }
    }
    __builtin_amdgcn_s_setprio(1);
    #pragma unroll
    for (int kc4 = 0; kc4 < 2; ++kc4) {
      bf16x8 pa[2];
      #pragma unroll
      for (int of = 0; of < 2; ++of)
        pa[of] = *(const bf16x8*)((const char*)Ps[w] + (of * 16 + fr) * 128 +
                                  ((kc4 * 64 + fg * 16) ^ swz));
      #pragma unroll
      for (int cf = 0; cf < 4; ++cf) {
        bf16x8 vb = *(const bf16x8*)((const char*)Vs[cur] + (cf * 16 + fr) * 128 +
                                     ((kc4 * 64 + fg * 16) ^ swz));
        #pragma unroll
        for (int of = 0; of < 2; ++of)
          o[of][cf] = __builtin_amdgcn_mfma_f32_16x16x32_bf16(pa[of], vb, o[of][cf], 0, 0, 0);
      }
      #pragma unroll
      for (int of = 0; of < 2; ++of)           // row-sum on the matrix pipe
        ls[of] = __builtin_amdgcn_mfma_f32_16x16x32_bf16(pa[of], ones, ls[of], 0, 0, 0);
    }
    __builtin_amdgcn_s_setprio(0);
    __syncthreads();   // drains prefetch + protects buffer reuse
  }
  #pragma unroll
  for (int of = 0; of < 2; ++of) {
    #pragma unroll
    for (int cf = 0; cf < 4; ++cf)
      #pragma unroll
      for (int r = 0; r < 4; ++r) {
        int grow_ = bt * 1024 + qt * 128 + w * 32 + of * 16 + fg * 4 + r;
        int gcol  = h * 64 + cf * 16 + fr;
        aout[(size_t)grow_ * 1024 + gcol] = f2bf(o[of][cf][r] / ls[of][r]);
      }
  }
}

// ---------------------------------------------------------------- launch
extern "C" void kernel_launch(void* const* d_in, const int* in_sizes, int n_in,
                              void* d_out, int out_size, void* d_ws, size_t ws_size,
                              hipStream_t stream)
{
  const float* x     = (const float*)d_in[0];
  const float* gamma = (const float*)d_in[1];
  const float* beta  = (const float*)d_in[2];
  const float* Wqkv  = (const float*)d_in[3];
  const float* bqkv  = (const float*)d_in[4];
  const float* Wout  = (const float*)d_in[5];
  const float* rope  = (const float*)d_in[6];

  char* ws = (char*)d_ws;
  ushort* xn   = (ushort*)(ws + 0);              //  33,554,432 B (16384x1024 bf16)
  ushort* qkvb = (ushort*)(ws + 33554432ULL);    // 100,663,296 B (16384x3072 bf16; v third unused)
  ushort* vT   = (ushort*)(ws + 134217728ULL);   //  33,554,432 B (256 bh x 64 d x 1024 l bf16)
  ushort* Wqt  = (ushort*)(ws + 167772160ULL);   //   6,291,456 B (3072x1024 bf16)
  ushort* Wot  = (ushort*)(ws + 174063616ULL);   //   2,097,152 B (1024x1024 bf16)
  float2* cst  = (float2*)(ws + 176160768ULL);   //     131,072 B (1024x16 float2)
  ushort* aout = xn;                             // reuse xn after QKV GEMM

  preproc_kernel<<<17472, 256, 0, stream>>>(x, gamma, beta, xn,
                                            Wqkv, Wqt, Wout, Wot, rope, cst);
  gemm256_kernel<true, true, true><<<768, 512, 0, stream>>>(
      xn, Wqt, bqkv, (void*)qkvb, cst, vT, 16384, 3072, 1024);
  attn_kernel<<<2048, 256, 0, stream>>>(qkvb, vT, aout);
  gemm256_kernel<false, false, false><<<256, 512, 0, stream>>>(
      aout, Wot, nullptr, d_out, nullptr, nullptr, 16384, 1024, 1024);
}

// Round 14
// 317.316 us; speedup vs baseline: 1.0370x; 1.0370x over previous
//
#include <hip/hip_runtime.h>
#include <hip/hip_bf16.h>
#include <stdint.h>

typedef short bf16x8 __attribute__((ext_vector_type(8)));
typedef float f32x4  __attribute__((ext_vector_type(4)));
typedef unsigned short u16x4 __attribute__((ext_vector_type(4)));
typedef unsigned int   u32x2 __attribute__((ext_vector_type(2)));

#define DEV __device__ __forceinline__

DEV ushort f2bf(float f){
  unsigned u = __float_as_uint(f);
  u += 0x7FFFu + ((u >> 16) & 1u);      // RNE
  return (ushort)(u >> 16);
}

DEV unsigned pack_bf16x2(float lo, float hi){
  __hip_bfloat162 r = __float22bfloat162_rn(float2{lo, hi});   // v_cvt_pk_bf16_f32
  return *(unsigned*)&r;
}

DEV void async16(const void* g, void* l){
  __builtin_amdgcn_global_load_lds((const __attribute__((address_space(1))) void*)g,
                                   (__attribute__((address_space(3))) void*)l, 16, 0, 0);
}

// ---------------------------------------------- fused preprocessing
// blocks [0,16384): LayerNorm row      -> xn (bf16)
// blocks [16384,17152): Wqkv^T tile    -> Wqt (bf16, 3072x1024)
// blocks [17152,17408): Wout^T tile    -> Wot (bf16, 1024x1024)
// blocks [17408,17472): rope cos/sin   -> cst (float2, 1024x16)
__global__ __launch_bounds__(256) void preproc_kernel(
    const float* __restrict__ x, const float* __restrict__ gamma,
    const float* __restrict__ beta, ushort* __restrict__ xn,
    const float* __restrict__ Wqkv, ushort* __restrict__ Wqt,
    const float* __restrict__ Wout, ushort* __restrict__ Wot,
    const float* __restrict__ rope, float2* __restrict__ cst)
{
  __shared__ __align__(16) ushort tile[64][65];
  __shared__ float red[8];
  const int b = blockIdx.x, t = threadIdx.x;
  if (b < 16384) {                     // ---- LayerNorm
    const float4* xr = (const float4*)(x + (size_t)b * 1024);
    float4 v = xr[t];
    float s  = v.x + v.y + v.z + v.w;
    float s2 = v.x*v.x + v.y*v.y + v.z*v.z + v.w*v.w;
    #pragma unroll
    for (int o = 1; o < 64; o <<= 1) { s += __shfl_xor(s, o); s2 += __shfl_xor(s2, o); }
    int lane = t & 63, wv = t >> 6;
    if (lane == 0) { red[wv] = s; red[4 + wv] = s2; }
    __syncthreads();
    s  = red[0] + red[1] + red[2] + red[3];
    s2 = red[4] + red[5] + red[6] + red[7];
    float mean = s * (1.0f / 1024.0f);
    float var  = s2 * (1.0f / 1024.0f) - mean * mean;
    float rs = rsqrtf(var + 1e-5f);
    float4 g = ((const float4*)gamma)[t], bb = ((const float4*)beta)[t];
    u16x4 o4;
    o4[0] = f2bf((v.x - mean) * rs * g.x + bb.x);
    o4[1] = f2bf((v.y - mean) * rs * g.y + bb.y);
    o4[2] = f2bf((v.z - mean) * rs * g.z + bb.z);
    o4[3] = f2bf((v.w - mean) * rs * g.w + bb.w);
    ((u16x4*)(xn + (size_t)b * 1024))[t] = o4;
  } else if (b < 17408) {              // ---- W transposes (fp32 -> bf16)
    const float* A; ushort* At; int R, C, c0, r0;
    if (b < 17152) { int bb2 = b - 16384; A = Wqkv; At = Wqt; R = 1024; C = 3072;
                     c0 = (bb2 % 48) * 64; r0 = (bb2 / 48) * 64; }
    else           { int bb2 = b - 17152; A = Wout; At = Wot; R = 1024; C = 1024;
                     c0 = (bb2 % 16) * 64; r0 = (bb2 / 16) * 64; }
    int tx = t & 63, ty = t >> 6;
    #pragma unroll
    for (int i = 0; i < 64; i += 4)
      tile[ty + i][tx] = f2bf(A[(size_t)(r0 + ty + i) * C + c0 + tx]);
    __syncthreads();
    #pragma unroll
    for (int i = 0; i < 64; i += 4)
      At[(size_t)(c0 + ty + i) * R + r0 + tx] = tile[tx][ty + i];
  } else {                             // ---- rope tables
    int i = (b - 17408) * 256 + t;     // 16384 = 1024 l * 16 d
    int l = i >> 4, d = i & 15;
    float p = rope[l * 32 + d];
    float s, c;
    sincosf(p, &s, &c);
    cst[i] = float2{c, s};
  }
}

// ------------------------------------------------- bf16 GEMM (R5-proven loop)
// 256x256 tile, BK=64, 8 waves (2Mx4N), K-plane LDS [buf][kc][256][64B],
// counted vmcnt(4) pipeline. ROUND-MAJOR mapping: blocks [r*256,(r+1)*256)
// cover one 2MB B-stripe over all 64 M-tiles; at 1 block/CU each round is a
// co-resident cohort whose B-stripe stays L2-resident.
// ROPE epilogue: rotate cols<2048, pre-scale q (cols<1024) by 0.125*log2(e).
template<bool OUT_BF16, bool HAS_BIAS, bool ROPE>
__global__ __launch_bounds__(512, 2) void gemm256_kernel(
    const ushort* __restrict__ A, const ushort* __restrict__ Bt,
    const float* __restrict__ bias, void* __restrict__ Cout,
    const float2* __restrict__ cst,
    int M, int Nrow, int K)
{
  __shared__ __align__(16) ushort As[2][2][256][32];   // 64 KiB
  __shared__ __align__(16) ushort Bs[2][2][256][32];   // 64 KiB
  const int tid = threadIdx.x, lane = tid & 63, w = tid >> 6;
  const int fr = lane & 15, fg = lane >> 4;
  const int wr = w >> 2, wc = w & 3;

  // round-major + XCD-contiguous within round
  int i  = blockIdx.x & 255;
  int r  = blockIdx.x >> 8;
  int il = (i & 7) * 32 + (i >> 3);
  int bx = r * 4 + (il & 3);
  int by = il >> 2;
  const int aRow0 = by * 256, bCol0 = bx * 256;
  const size_t ldb = (size_t)K * 2;   // row bytes

  // ---- staging constants (2 load-groups per wave, 16 rows x 64B each)
  const int lrow = lane >> 2, lch = lane & 3;
  const int g0 = w * 2, g1 = w * 2 + 1;
  const int r0 = g0 * 16 + lrow, r1 = g1 * 16 + lrow;
  const int sc0 = ((lch ^ ((r0 & 3) ^ ((r0 >> 2) & 3))) << 4);
  const int sc1 = ((lch ^ ((r1 & 3) ^ ((r1 >> 2) & 3))) << 4);
  const char* Ab = (const char*)A + (size_t)aRow0 * ldb;
  const char* Bb = (const char*)Bt + (size_t)bCol0 * ldb;
  const size_t ga0 = (size_t)r0 * ldb, ga1 = (size_t)r1 * ldb;
  char* ldsA = (char*)&As[0][0][0][0];
  char* ldsB = (char*)&Bs[0][0][0][0];
  const int ld0 = g0 * 1024, ld1 = g1 * 1024;

  // ---- fragment read byte-offsets (within a plane)
  int rbA[8], rbB[4];
  #pragma unroll
  for (int mf = 0; mf < 8; ++mf) {
    int rr = wr * 128 + mf * 16 + fr;
    rbA[mf] = rr * 64 + ((fg ^ ((rr & 3) ^ ((rr >> 2) & 3))) << 4);
  }
  #pragma unroll
  for (int nf = 0; nf < 4; ++nf) {
    int rr = wc * 64 + nf * 16 + fr;
    rbB[nf] = rr * 64 + ((fg ^ ((rr & 3) ^ ((rr >> 2) & 3))) << 4);
  }

  f32x4 acc[8][4];
  f32x4 z = {0.f, 0.f, 0.f, 0.f};
  #pragma unroll
  for (int mf = 0; mf < 8; ++mf)
    #pragma unroll
    for (int nf = 0; nf < 4; ++nf) acc[mf][nf] = z;

  auto stage = [&](int buf, int kt, int kc) {
    const char* ak = Ab + (size_t)kt * 128 + kc * 64;
    const char* bk = Bb + (size_t)kt * 128 + kc * 64;
    int lo = buf * 32768 + kc * 16384;
    async16(ak + ga0 + sc0, ldsA + lo + ld0);
    async16(ak + ga1 + sc1, ldsA + lo + ld1);
    async16(bk + ga0 + sc0, ldsB + lo + ld0);
    async16(bk + ga1 + sc1, ldsB + lo + ld1);
  };

  // prologue: stage tile 0 (both planes), wait first plane, enter loop
  stage(0, 0, 0);
  stage(0, 0, 1);
  asm volatile("s_waitcnt vmcnt(4)" ::: "memory");
  __builtin_amdgcn_s_barrier();

  const int nk = K >> 6;
  for (int kt = 0; kt < nk; ++kt) {
    int buf = kt & 1;
    bool pre = (kt + 1 < nk);
    #pragma unroll
    for (int kc = 0; kc < 2; ++kc) {
      const char* ab = ldsA + buf * 32768 + kc * 16384;
      const char* bb = ldsB + buf * 32768 + kc * 16384;
      bf16x8 a[8], b[4];
      #pragma unroll
      for (int mf = 0; mf < 8; ++mf) a[mf] = *(const bf16x8*)(ab + rbA[mf]);
      #pragma unroll
      for (int nf = 0; nf < 4; ++nf) b[nf] = *(const bf16x8*)(bb + rbB[nf]);
      if (pre) stage(buf ^ 1, kt + 1, kc);
      __builtin_amdgcn_s_setprio(1);
      #pragma unroll
      for (int mf = 0; mf < 8; ++mf)
        #pragma unroll
        for (int nf = 0; nf < 4; ++nf)
          acc[mf][nf] = __builtin_amdgcn_mfma_f32_16x16x32_bf16(a[mf], b[nf], acc[mf][nf], 0, 0, 0);
      __builtin_amdgcn_s_setprio(0);
      if (pre) { asm volatile("s_waitcnt vmcnt(4)" ::: "memory"); }
      else     { asm volatile("s_waitcnt vmcnt(0)" ::: "memory"); }
      __builtin_amdgcn_s_barrier();
    }
  }

  // ---- epilogue
  #pragma unroll
  for (int pr = 0; pr < 2; ++pr) {
    int nf0 = pr * 2, nf1 = nf0 + 1;
    int gc0 = bCol0 + wc * 64 + nf0 * 16 + fr;
    int gc1 = gc0 + 16;
    float bv0 = HAS_BIAS ? bias[gc0] : 0.0f;
    float bv1 = HAS_BIAS ? bias[gc1] : 0.0f;
    bool rot = ROPE && (pr == 0) && (gc0 < 2048);
    float qs = (ROPE && gc0 < 1024) ? 0.18033688f : 1.0f;   // 0.125*log2(e)
    #pragma unroll
    for (int mf = 0; mf < 8; ++mf) {
      int gr0 = aRow0 + wr * 128 + mf * 16 + fg * 4;
      #pragma unroll
      for (int rr2 = 0; rr2 < 4; ++rr2) {
        int gr = gr0 + rr2;
        float a = acc[mf][nf0][rr2] + bv0;
        float b = acc[mf][nf1][rr2] + bv1;
        if (rot) {
          int l = gr & 1023;
          float2 cp = cst[l * 16 + fr];
          float an = fmaf(a, cp.x, -b * cp.y);
          b = fmaf(b, cp.x, a * cp.y);
          a = an;
        }
        a *= qs; b *= qs;
        if (OUT_BF16) {
          ((ushort*)Cout)[(size_t)gr * Nrow + gc0] = f2bf(a);
          ((ushort*)Cout)[(size_t)gr * Nrow + gc1] = f2bf(b);
        } else {
          ((float*)Cout)[(size_t)gr * Nrow + gc0] = a;
          ((float*)Cout)[(size_t)gr * Nrow + gc1] = b;
        }
      }
    }
  }
}

// ------------------------------------------------------- V -> V^T (per bt,head)
__global__ __launch_bounds__(256) void vtrans_kernel(const ushort* __restrict__ qkv,
                                                     ushort* __restrict__ vT)
{
  __shared__ __align__(16) ushort tile[64][65];
  int bh = blockIdx.x & 255, lt = blockIdx.x >> 8;
  int bt = bh >> 4, h = bh & 15;
  int tx = threadIdx.x & 63, ty = threadIdx.x >> 6;
  const ushort* src = qkv + (size_t)(bt * 1024 + lt * 64) * 3072 + 2048 + h * 64;
  #pragma unroll
  for (int i = 0; i < 64; i += 4)
    tile[ty + i][tx] = src[(size_t)(ty + i) * 3072 + tx];
  __syncthreads();
  ushort* dst = vT + (size_t)bh * 64 * 1024 + lt * 64;
  #pragma unroll
  for (int i = 0; i < 64; i += 4)
    dst[(size_t)(ty + i) * 1024 + tx] = tile[tx][ty + i];
}

// ---------------------------------------------------------------- Flash attention v7 (R11-proven, 132us)
// 256 thr / 4 waves, QBLK=128; defer-max, exp2-domain, cvt_pk P-pack,
// ones-MFMA l on the matrix pipe; 3 blocks/CU.
__global__ __launch_bounds__(256, 3) void attn_kernel(
    const ushort* __restrict__ qkv, const ushort* __restrict__ vT,
    ushort* __restrict__ aout)
{
  __shared__ __align__(16) ushort Ks[2][64 * 64];
  __shared__ __align__(16) ushort Vs[2][64 * 64];   // Vs[d][kv]
  __shared__ __align__(16) ushort Ps[4][32 * 64];   // per-wave P
  const int tid = threadIdx.x, lane = tid & 63, w = tid >> 6;
  const int fr = lane & 15, fg = lane >> 4;
  const int bh = blockIdx.x & 255, qt = blockIdx.x >> 8;  // same-bh -> same XCD
  const int bt = bh >> 4, h = bh & 15;
  const size_t ld = 3072;
  const ushort* qbase = qkv + (size_t)bt * 1024 * ld + h * 64;
  const ushort* kbase = qbase + 1024;
  const ushort* vtb = vT + (size_t)bh * 64 * 1024;
  const int srow = lane >> 3;
  const int scol = (((lane & 7) ^ srow) << 4);
  const int swz = (fr & 7) << 4;

  bf16x8 ones;
  #pragma unroll
  for (int j = 0; j < 8; ++j) ones[j] = (short)0x3F80;   // 1.0 bf16

  // Q fragments straight from global (one-time; reused 16 tiles)
  bf16x8 qfr[2][2];
  #pragma unroll
  for (int qf = 0; qf < 2; ++qf)
    #pragma unroll
    for (int kc = 0; kc < 2; ++kc) {
      int qrow = qt * 128 + w * 32 + qf * 16 + fr;
      qfr[qf][kc] = *(const bf16x8*)((const char*)(qbase + (size_t)qrow * ld) + kc * 64 + fg * 16);
    }

  f32x4 o[2][4], ls[2];
  f32x4 z = {0.f, 0.f, 0.f, 0.f};
  #pragma unroll
  for (int a = 0; a < 2; ++a) {
    ls[a] = z;
    #pragma unroll
    for (int b = 0; b < 4; ++b) o[a][b] = z;
  }
  float m_[2] = {-1e30f, -1e30f};

  auto stage = [&](int buf, int t) {
    #pragma unroll
    for (int i = 0; i < 2; ++i) {
      int ch = w * 2 + i;                 // 8 chunks of 1KB each for K and V
      async16((const char*)(kbase + (size_t)(t * 64 + ch * 8 + srow) * ld) + scol,
              (char*)Ks[buf] + ch * 1024);
      async16((const char*)(vtb + (size_t)(ch * 8 + srow) * 1024) + t * 128 + scol,
              (char*)Vs[buf] + ch * 1024);
    }
  };

  stage(0, 0);
  __syncthreads();
  for (int t = 0; t < 16; ++t) {
    int cur = t & 1;
    if (t + 1 < 16) stage(cur ^ 1, t + 1);   // overlaps compute below

    bf16x8 kf[4][2];
    #pragma unroll
    for (int kvf = 0; kvf < 4; ++kvf)
      #pragma unroll
      for (int kc = 0; kc < 2; ++kc)
        kf[kvf][kc] = *(const bf16x8*)((const char*)Ks[cur] + (kvf * 16 + fr) * 128 +
                                       ((kc * 64 + fg * 16) ^ swz));
    float alpha[2] = {1.0f, 1.0f};
    int   need[2];
    #pragma unroll
    for (int qf = 0; qf < 2; ++qf) {
      f32x4 st[4];
      #pragma unroll
      for (int kvf = 0; kvf < 4; ++kvf) st[kvf] = z;
      __builtin_amdgcn_s_setprio(1);
      #pragma unroll
      for (int kc = 0; kc < 2; ++kc)
        #pragma unroll
        for (int kvf = 0; kvf < 4; ++kvf)
          st[kvf] = __builtin_amdgcn_mfma_f32_16x16x32_bf16(kf[kvf][kc], qfr[qf][kc], st[kvf], 0, 0, 0);
      __builtin_amdgcn_s_setprio(0);
      float mx = -1e30f;
      #pragma unroll
      for (int kvf = 0; kvf < 4; ++kvf)
        #pragma unroll
        for (int r = 0; r < 4; ++r) mx = fmaxf(mx, st[kvf][r]);
      mx = fmaxf(mx, __shfl_xor(mx, 16));
      mx = fmaxf(mx, __shfl_xor(mx, 32));
      // defer-max: only advance running max when tile max exceeds it by >11.53
      // (log2-domain; P then bounded by 2^11.53 ~= e^8 -- bf16-safe)
      need[qf] = __any(mx > m_[qf] + 11.53f);
      if (need[qf]) {
        float mn = fmaxf(m_[qf], mx);
        alpha[qf] = __builtin_amdgcn_exp2f(m_[qf] - mn);
        m_[qf] = mn;
      }
      float mb = m_[qf];
      int qrow = qf * 16 + fr;
      #pragma unroll
      for (int kvf = 0; kvf < 4; ++kvf) {
        float p0 = __builtin_amdgcn_exp2f(st[kvf][0] - mb);
        float p1 = __builtin_amdgcn_exp2f(st[kvf][1] - mb);
        float p2 = __builtin_amdgcn_exp2f(st[kvf][2] - mb);
        float p3 = __builtin_amdgcn_exp2f(st[kvf][3] - mb);
        u32x2 u;
        u[0] = pack_bf16x2(p0, p1);
        u[1] = pack_bf16x2(p2, p3);
        *(u32x2*)((char*)Ps[w] + qrow * 128 + ((kvf * 32 + fg * 8) ^ swz)) = u;
      }
    }
    #pragma unroll
    for (int of = 0; of < 2; ++of) {
      if (need[of]) {                          // wave-uniform branch
        float ar[4];
        #pragma unroll
        for (int r = 0; r < 4; ++r) ar[r] = __shfl(alpha[of], fg * 4 + r);
        #pragma unroll
        for (int cf = 0; cf < 4; ++cf)
          #pragma unroll
          for (int r = 0; r < 4; ++r) o[of][cf][r] *= ar[r];
        #pragma unroll
        for (int r = 0; r < 4; ++r) ls[of][r] *= ar[r];
      }
    }
    __builtin_amdgcn_s_setprio(1);
    #pragma unroll
    for (int kc4 = 0; kc4 < 2; ++kc4) {
      bf16x8 pa[2];
      #pragma unroll
      for (int of = 0; of < 2; ++of)
        pa[of] = *(const bf16x8*)((const char*)Ps[w] + (of * 16 + fr) * 128 +
                                  ((kc4 * 64 + fg * 16) ^ swz));
      #pragma unroll
      for (int cf = 0; cf < 4; ++cf) {
        bf16x8 vb = *(const bf16x8*)((const char*)Vs[cur] + (cf * 16 + fr) * 128 +
                                     ((kc4 * 64 + fg * 16) ^ swz));
        #pragma unroll
        for (int of = 0; of < 2; ++of)
          o[of][cf] = __builtin_amdgcn_mfma_f32_16x16x32_bf16(pa[of], vb, o[of][cf], 0, 0, 0);
      }
      #pragma unroll
      for (int of = 0; of < 2; ++of)           // row-sum on the matrix pipe
        ls[of] = __builtin_amdgcn_mfma_f32_16x16x32_bf16(pa[of], ones, ls[of], 0, 0, 0);
    }
    __builtin_amdgcn_s_setprio(0);
    __syncthreads();   // drains prefetch + protects buffer reuse
  }
  #pragma unroll
  for (int of = 0; of < 2; ++of) {
    #pragma unroll
    for (int cf = 0; cf < 4; ++cf)
      #pragma unroll
      for (int r = 0; r < 4; ++r) {
        int grow_ = bt * 1024 + qt * 128 + w * 32 + of * 16 + fg * 4 + r;
        int gcol  = h * 64 + cf * 16 + fr;
        aout[(size_t)grow_ * 1024 + gcol] = f2bf(o[of][cf][r] / ls[of][r]);
      }
  }
}

// ---------------------------------------------------------------- launch
extern "C" void kernel_launch(void* const* d_in, const int* in_sizes, int n_in,
                              void* d_out, int out_size, void* d_ws, size_t ws_size,
                              hipStream_t stream)
{
  const float* x     = (const float*)d_in[0];
  const float* gamma = (const float*)d_in[1];
  const float* beta  = (const float*)d_in[2];
  const float* Wqkv  = (const float*)d_in[3];
  const float* bqkv  = (const float*)d_in[4];
  const float* Wout  = (const float*)d_in[5];
  const float* rope  = (const float*)d_in[6];

  char* ws = (char*)d_ws;
  ushort* xn   = (ushort*)(ws + 0);              //  33,554,432 B (16384x1024 bf16)
  ushort* qkvb = (ushort*)(ws + 33554432ULL);    // 100,663,296 B (16384x3072 bf16)
  ushort* vT   = (ushort*)(ws + 134217728ULL);   //  33,554,432 B (256 bh x 64 d x 1024 l bf16)
  ushort* Wqt  = (ushort*)(ws + 167772160ULL);   //   6,291,456 B (3072x1024 bf16)
  ushort* Wot  = (ushort*)(ws + 174063616ULL);   //   2,097,152 B (1024x1024 bf16)
  float2* cst  = (float2*)(ws + 176160768ULL);   //     131,072 B (1024x16 float2)
  ushort* aout = xn;                             // reuse xn after QKV GEMM

  preproc_kernel<<<17472, 256, 0, stream>>>(x, gamma, beta, xn,
                                            Wqkv, Wqt, Wout, Wot, rope, cst);
  gemm256_kernel<true, true, true><<<768, 512, 0, stream>>>(
      xn, Wqt, bqkv, (void*)qkvb, cst, 16384, 3072, 1024);
  vtrans_kernel<<<4096, 256, 0, stream>>>(qkvb, vT);
  attn_kernel<<<2048, 256, 0, stream>>>(qkvb, vT, aout);
  gemm256_kernel<false, false, false><<<256, 512, 0, stream>>>(
      aout, Wot, nullptr, d_out, nullptr, 16384, 1024, 1024);
}